// Round 1
// baseline (28025.339 us; speedup 1.0000x reference)
//
#include <hip/hip_runtime.h>
#include <math.h>

// Problem constants
#define B_ROWS 8192
#define S_LEN  512
#define H_DIM  256
#define G3     768          // 3*H
#define P_DIM  96
#define TB     32           // batch rows per block

__device__ __forceinline__ float sigmoid_fast(float v) {
    return 1.0f / (1.0f + __expf(-v));
}
// tanh(x) = 1 - 2/(e^{2x}+1); safe at extremes: e^{2x}->inf gives 1, ->0 gives -1.
__device__ __forceinline__ float tanh_fast(float v) {
    return 1.0f - 2.0f / (__expf(2.0f * v) + 1.0f);
}

// Pre-transpose weights into workspace:
//   WT [256][768]  : WT[k][j]  = W_hh[j][k]   (coalesced float4 loads in main loop)
//   WoT[256][96]   : WoT[k][p] = W_out[p][k]  (coalesced scalar loads in epilogue)
__global__ void transpose_weights(const float* __restrict__ W_hh,
                                  const float* __restrict__ W_out,
                                  float* __restrict__ WT,
                                  float* __restrict__ WoT) {
    int idx = blockIdx.x * blockDim.x + threadIdx.x;
    if (idx < H_DIM * G3) {
        int k = idx / G3;
        int j = idx % G3;
        WT[idx] = W_hh[j * H_DIM + k];
    } else if (idx < H_DIM * G3 + H_DIM * P_DIM) {
        int i = idx - H_DIM * G3;
        int k = i / P_DIM;
        int p = i % P_DIM;
        WoT[i] = W_out[p * H_DIM + k];
    }
}

// Persistent GRU kernel.
// grid = 256 blocks (1 per CU), block = 256 threads (4 waves).
// Each block owns TB=32 batch rows; h tile [32][256] lives in LDS for all 512 steps.
// Thread mapping: cid = tid&63 -> 4 gate-cols (4*cid..4*cid+3); rid = tid>>6 -> 8 rows.
//   => 32 accumulators/thread, h reads are wave-uniform (LDS broadcast),
//      weight reads are lane-contiguous float4 from WT (L1/L2 resident).
template <bool TW>
__global__ __launch_bounds__(256, 1)
void gru_persist(const float* __restrict__ x,
                 const float* __restrict__ W_ih,
                 const float* __restrict__ Whh,    // TW ? WT[256][768] : W_hh[768][256]
                 const float* __restrict__ b_ih,
                 const float* __restrict__ b_hh,
                 const float* __restrict__ Wout,   // TW ? WoT[256][96] : W_out[96][256]
                 const float* __restrict__ b_out,
                 float* __restrict__ out) {
    __shared__ float hbuf[TB][H_DIM];
    __shared__ float p_wih[G3];
    __shared__ float p_bih[G3];
    __shared__ float p_bhh[G3];

    const int tid   = threadIdx.x;
    const int cid   = tid & 63;
    const int rid   = tid >> 6;
    const int row0  = blockIdx.x * TB;
    const int myrow = rid * 8;          // 8 consecutive rows
    const int c0    = cid * 4;          // 4 consecutive gate cols

    for (int i = tid; i < G3; i += 256) {
        p_wih[i] = W_ih[i];
        p_bih[i] = b_ih[i];
        p_bhh[i] = b_hh[i];
    }
    for (int i = tid; i < TB * H_DIM; i += 256) ((float*)hbuf)[i] = 0.0f;
    __syncthreads();

    float r_g[8][4], z_g[8][4], n_g[8][4];

    for (int t = 0; t < S_LEN; ++t) {
        // input scalar for each of my 8 rows (wave-broadcast global loads)
        float xv[8];
#pragma unroll
        for (int rr = 0; rr < 8; ++rr)
            xv[rr] = x[(size_t)(row0 + myrow + rr) * S_LEN + t];

#pragma unroll
        for (int g = 0; g < 3; ++g) {
            float acc[8][4];
#pragma unroll
            for (int rr = 0; rr < 8; ++rr)
#pragma unroll
                for (int cc = 0; cc < 4; ++cc) acc[rr][cc] = 0.0f;

            const float* wq = TW ? (Whh + g * H_DIM + c0)                    // WT[k][768]
                                 : (Whh + (size_t)(g * H_DIM + c0) * H_DIM); // W_hh rows

            for (int k = 0; k < H_DIM; k += 4) {
                float wmat[4][4];  // [kk][cc]
                if (TW) {
#pragma unroll
                    for (int kk = 0; kk < 4; ++kk) {
                        const float4 wv = *(const float4*)(wq + (size_t)(k + kk) * G3);
                        wmat[kk][0] = wv.x; wmat[kk][1] = wv.y;
                        wmat[kk][2] = wv.z; wmat[kk][3] = wv.w;
                    }
                } else {
#pragma unroll
                    for (int cc = 0; cc < 4; ++cc) {
                        const float4 wv = *(const float4*)(wq + (size_t)cc * H_DIM + k);
                        wmat[0][cc] = wv.x; wmat[1][cc] = wv.y;
                        wmat[2][cc] = wv.z; wmat[3][cc] = wv.w;
                    }
                }
                float4 hv[8];
#pragma unroll
                for (int rr = 0; rr < 8; ++rr)
                    hv[rr] = *(const float4*)&hbuf[myrow + rr][k];
#pragma unroll
                for (int kk = 0; kk < 4; ++kk) {
#pragma unroll
                    for (int rr = 0; rr < 8; ++rr) {
                        const float hvv = (&hv[rr].x)[kk];
#pragma unroll
                        for (int cc = 0; cc < 4; ++cc)
                            acc[rr][cc] = fmaf(hvv, wmat[kk][cc], acc[rr][cc]);
                    }
                }
            }

            // gate nonlinearities (params from LDS, per-lane distinct -> fine)
            float wg[4], big[4], bhg[4];
#pragma unroll
            for (int cc = 0; cc < 4; ++cc) {
                const int j = g * H_DIM + c0 + cc;
                wg[cc] = p_wih[j]; big[cc] = p_bih[j]; bhg[cc] = p_bhh[j];
            }
            if (g == 0) {
#pragma unroll
                for (int rr = 0; rr < 8; ++rr)
#pragma unroll
                    for (int cc = 0; cc < 4; ++cc)
                        r_g[rr][cc] = sigmoid_fast(acc[rr][cc] + bhg[cc] +
                                                   fmaf(xv[rr], wg[cc], big[cc]));
            } else if (g == 1) {
#pragma unroll
                for (int rr = 0; rr < 8; ++rr)
#pragma unroll
                    for (int cc = 0; cc < 4; ++cc)
                        z_g[rr][cc] = sigmoid_fast(acc[rr][cc] + bhg[cc] +
                                                   fmaf(xv[rr], wg[cc], big[cc]));
            } else {
#pragma unroll
                for (int rr = 0; rr < 8; ++rr)
#pragma unroll
                    for (int cc = 0; cc < 4; ++cc) {
                        const float hn  = acc[rr][cc] + bhg[cc];
                        const float i_n = fmaf(xv[rr], wg[cc], big[cc]);
                        n_g[rr][cc] = tanh_fast(fmaf(r_g[rr][cc], hn, i_n));
                    }
            }
        }

        __syncthreads();  // all h reads of this step complete
        // h update: each thread updates exactly its own (row, col) cells
#pragma unroll
        for (int rr = 0; rr < 8; ++rr) {
            float4 hold = *(const float4*)&hbuf[myrow + rr][c0];
            float4 hnew;
            hnew.x = (1.0f - z_g[rr][0]) * n_g[rr][0] + z_g[rr][0] * hold.x;
            hnew.y = (1.0f - z_g[rr][1]) * n_g[rr][1] + z_g[rr][1] * hold.y;
            hnew.z = (1.0f - z_g[rr][2]) * n_g[rr][2] + z_g[rr][2] * hold.z;
            hnew.w = (1.0f - z_g[rr][3]) * n_g[rr][3] + z_g[rr][3] * hold.w;
            *(float4*)&hbuf[myrow + rr][c0] = hnew;
        }
        __syncthreads();  // h visible before next step's reads
    }

    // Epilogue: out[row][p] = h[row] . W_out[p] + b_out[p]
    // Thread covers p = cid, and p = 64+cid when cid < 32.
    const int  pA   = cid;
    const int  pB   = 64 + cid;
    const bool hasB = (cid < 32);
    float accA[8], accB[8];
#pragma unroll
    for (int rr = 0; rr < 8; ++rr) { accA[rr] = 0.0f; accB[rr] = 0.0f; }

    for (int k = 0; k < H_DIM; k += 4) {
        float4 hv[8];
#pragma unroll
        for (int rr = 0; rr < 8; ++rr)
            hv[rr] = *(const float4*)&hbuf[myrow + rr][k];
        float wA[4], wB[4];
#pragma unroll
        for (int kk = 0; kk < 4; ++kk) {
            wA[kk] = TW ? Wout[(size_t)(k + kk) * P_DIM + pA]
                        : Wout[(size_t)pA * H_DIM + k + kk];
            wB[kk] = hasB ? (TW ? Wout[(size_t)(k + kk) * P_DIM + pB]
                                : Wout[(size_t)pB * H_DIM + k + kk])
                          : 0.0f;
        }
#pragma unroll
        for (int kk = 0; kk < 4; ++kk)
#pragma unroll
            for (int rr = 0; rr < 8; ++rr) {
                const float hvv = (&hv[rr].x)[kk];
                accA[rr] = fmaf(hvv, wA[kk], accA[rr]);
                accB[rr] = fmaf(hvv, wB[kk], accB[rr]);
            }
    }
    const float boA = b_out[pA];
    const float boB = hasB ? b_out[pB] : 0.0f;
#pragma unroll
    for (int rr = 0; rr < 8; ++rr) {
        const size_t orow = (size_t)(row0 + myrow + rr) * P_DIM;
        out[orow + pA] = accA[rr] + boA;
        if (hasB) out[orow + pB] = accB[rr] + boB;
    }
}

extern "C" void kernel_launch(void* const* d_in, const int* in_sizes, int n_in,
                              void* d_out, int out_size, void* d_ws, size_t ws_size,
                              hipStream_t stream) {
    const float* x     = (const float*)d_in[0];
    const float* W_ih  = (const float*)d_in[1];
    const float* W_hh  = (const float*)d_in[2];
    const float* b_ih  = (const float*)d_in[3];
    const float* b_hh  = (const float*)d_in[4];
    const float* W_out = (const float*)d_in[5];
    const float* b_out = (const float*)d_in[6];
    float* out = (float*)d_out;

    const size_t WT_elems  = (size_t)H_DIM * G3;     // 196608
    const size_t WoT_elems = (size_t)H_DIM * P_DIM;  // 24576
    const size_t need = (WT_elems + WoT_elems) * sizeof(float);

    if (ws_size >= need) {
        float* WT  = (float*)d_ws;
        float* WoT = WT + WT_elems;
        const int total = (int)(WT_elems + WoT_elems);
        transpose_weights<<<(total + 255) / 256, 256, 0, stream>>>(W_hh, W_out, WT, WoT);
        gru_persist<true><<<B_ROWS / TB, 256, 0, stream>>>(x, W_ih, WT, b_ih, b_hh,
                                                           WoT, b_out, out);
    } else {
        gru_persist<false><<<B_ROWS / TB, 256, 0, stream>>>(x, W_ih, W_hh, b_ih, b_hh,
                                                            W_out, b_out, out);
    }
}

// Round 2
// 20741.295 us; speedup vs baseline: 1.3512x; 1.3512x over previous
//
#include <hip/hip_runtime.h>
#include <math.h>

// Problem constants
#define B_ROWS 8192
#define S_LEN  512
#define H_DIM  256
#define G3     768          // 3*H
#define P_DIM  96
#define TB     32           // batch rows per block

__device__ __forceinline__ float sigmoid_fast(float v) {
    return 1.0f / (1.0f + __expf(-v));
}
// tanh(x) = 1 - 2/(e^{2x}+1); safe at extremes.
__device__ __forceinline__ float tanh_fast(float v) {
    return 1.0f - 2.0f / (__expf(2.0f * v) + 1.0f);
}

// Pre-transpose weights into workspace:
//   WT [256][768]  : WT[k][j]  = W_hh[j][k]   (coalesced float4 loads in main loop)
//   WoT[256][96]   : WoT[k][p] = W_out[p][k]  (coalesced loads in epilogue)
__global__ void transpose_weights(const float* __restrict__ W_hh,
                                  const float* __restrict__ W_out,
                                  float* __restrict__ WT,
                                  float* __restrict__ WoT) {
    int idx = blockIdx.x * blockDim.x + threadIdx.x;
    if (idx < H_DIM * G3) {
        int k = idx / G3;
        int j = idx % G3;
        WT[idx] = W_hh[j * H_DIM + k];
    } else if (idx < H_DIM * G3 + H_DIM * P_DIM) {
        int i = idx - H_DIM * G3;
        int k = i / P_DIM;
        int p = i % P_DIM;
        WoT[i] = W_out[p * H_DIM + k];
    }
}

// Persistent GRU kernel, gate-fused k-loop.
// grid = 256 blocks (1/CU), block = 256 threads (4 waves), 1 wave/SIMD.
// Each block owns TB=32 rows; h double-buffered in LDS.
// Thread: cid = tid&63 -> 4 cols per gate (12 total); rid = tid>>6 -> 8 rows.
// h reads are wave-uniform (LDS broadcast) and shared across all 3 gates.
template <bool TW>
__global__ __launch_bounds__(256, 1)
void gru_persist(const float* __restrict__ x,
                 const float* __restrict__ W_ih,
                 const float* __restrict__ Whh,    // TW ? WT[256][768] : W_hh[768][256]
                 const float* __restrict__ b_ih,
                 const float* __restrict__ b_hh,
                 const float* __restrict__ Wout,   // TW ? WoT[256][96] : W_out[96][256]
                 const float* __restrict__ b_out,
                 float* __restrict__ out) {
    __shared__ float hbuf[2][TB][H_DIM];   // 64 KiB, double-buffered hidden state
    __shared__ float xtile[2][TB][16];     // 4 KiB, 16-step x staging, double-buffered

    const int tid   = threadIdx.x;
    const int cid   = tid & 63;
    const int rid   = tid >> 6;
    const int row0  = blockIdx.x * TB;
    const int myrow = rid * 8;          // 8 consecutive rows
    const int c0    = cid * 4;          // 4 consecutive cols per gate

    // Hoist per-thread gate parameters into registers.
    // r,z gates: combined bias (b_ih + b_hh). n gate: keep separate.
    float wih[3][4], bc[2][4], bihn[4], bhhn[4];
#pragma unroll
    for (int cc = 0; cc < 4; ++cc) {
        const int j = c0 + cc;
        wih[0][cc] = W_ih[j];
        wih[1][cc] = W_ih[H_DIM + j];
        wih[2][cc] = W_ih[2 * H_DIM + j];
        bc[0][cc]  = b_ih[j] + b_hh[j];
        bc[1][cc]  = b_ih[H_DIM + j] + b_hh[H_DIM + j];
        bihn[cc]   = b_ih[2 * H_DIM + j];
        bhhn[cc]   = b_hh[2 * H_DIM + j];
    }

    // h = 0 in buffer 0; own cells mirrored in registers.
    for (int i = tid; i < TB * H_DIM; i += 256) (&hbuf[0][0][0])[i] = 0.0f;
    float h_own[8][4];
#pragma unroll
    for (int rr = 0; rr < 8; ++rr)
#pragma unroll
        for (int cc = 0; cc < 4; ++cc) h_own[rr][cc] = 0.0f;

    // Stage x tile for t=0..15 into buffer 0 (coalesced float2 per thread).
    {
        const int r  = tid >> 3;
        const int t2 = (tid & 7) * 2;
        const float2 v = *(const float2*)&x[(size_t)(row0 + r) * S_LEN + t2];
        xtile[0][r][t2]     = v.x;
        xtile[0][r][t2 + 1] = v.y;
    }
    __syncthreads();

    int p = 0;
    for (int t = 0; t < S_LEN; ++t) {
        // x values for my 8 rows (LDS broadcast reads)
        float xv[8];
#pragma unroll
        for (int rr = 0; rr < 8; ++rr)
            xv[rr] = xtile[(t >> 4) & 1][myrow + rr][t & 15];

        // acc init: fold bias + input-side pre-activation in.
        float acc[3][8][4];
#pragma unroll
        for (int rr = 0; rr < 8; ++rr)
#pragma unroll
            for (int cc = 0; cc < 4; ++cc) {
                acc[0][rr][cc] = fmaf(xv[rr], wih[0][cc], bc[0][cc]);
                acc[1][rr][cc] = fmaf(xv[rr], wih[1][cc], bc[1][cc]);
                acc[2][rr][cc] = bhhn[cc];
            }

        const float* hb = &hbuf[p][0][0];

#pragma unroll 2
        for (int kc = 0; kc < H_DIM / 4; ++kc) {
            const int k = kc * 4;
            // h fragment: one b128 broadcast per row, shared by all 3 gates
            float4 hv[8];
#pragma unroll
            for (int rr = 0; rr < 8; ++rr)
                hv[rr] = *(const float4*)(hb + (myrow + rr) * H_DIM + k);

            // weight fragments: [gate][kk] -> 4 cols each, lane-contiguous
            float4 wv[3][4];
            if (TW) {
#pragma unroll
                for (int g = 0; g < 3; ++g)
#pragma unroll
                    for (int kk = 0; kk < 4; ++kk)
                        wv[g][kk] = *(const float4*)(Whh + (size_t)(k + kk) * G3 +
                                                     g * H_DIM + c0);
            } else {
#pragma unroll
                for (int g = 0; g < 3; ++g)
#pragma unroll
                    for (int kk = 0; kk < 4; ++kk) {
                        float tmp[4];
#pragma unroll
                        for (int cc = 0; cc < 4; ++cc)
                            tmp[cc] = Whh[(size_t)(g * H_DIM + c0 + cc) * H_DIM + k + kk];
                        wv[g][kk] = make_float4(tmp[0], tmp[1], tmp[2], tmp[3]);
                    }
            }

#pragma unroll
            for (int kk = 0; kk < 4; ++kk)
#pragma unroll
                for (int rr = 0; rr < 8; ++rr) {
                    const float hvv = (&hv[rr].x)[kk];
#pragma unroll
                    for (int g = 0; g < 3; ++g) {
                        acc[g][rr][0] = fmaf(hvv, wv[g][kk].x, acc[g][rr][0]);
                        acc[g][rr][1] = fmaf(hvv, wv[g][kk].y, acc[g][rr][1]);
                        acc[g][rr][2] = fmaf(hvv, wv[g][kk].z, acc[g][rr][2]);
                        acc[g][rr][3] = fmaf(hvv, wv[g][kk].w, acc[g][rr][3]);
                    }
                }
        }

        // Gates + h update; write new h to the other buffer.
#pragma unroll
        for (int rr = 0; rr < 8; ++rr) {
            float4 hnew;
#pragma unroll
            for (int cc = 0; cc < 4; ++cc) {
                const float r_ = sigmoid_fast(acc[0][rr][cc]);
                const float z_ = sigmoid_fast(acc[1][rr][cc]);
                const float i_n = fmaf(xv[rr], wih[2][cc], bihn[cc]);
                const float n_ = tanh_fast(fmaf(r_, acc[2][rr][cc], i_n));
                const float hv2 = (1.0f - z_) * n_ + z_ * h_own[rr][cc];
                h_own[rr][cc] = hv2;
                (&hnew.x)[cc] = hv2;
            }
            *(float4*)&hbuf[1 - p][myrow + rr][c0] = hnew;
        }

        // Re-stage x for the next 16 steps into the idle x-buffer.
        if ((t & 15) == 15 && t != S_LEN - 1) {
            const int r  = tid >> 3;
            const int t2 = (tid & 7) * 2;
            const float2 v = *(const float2*)&x[(size_t)(row0 + r) * S_LEN + (t + 1) + t2];
            xtile[((t + 1) >> 4) & 1][r][t2]     = v.x;
            xtile[((t + 1) >> 4) & 1][r][t2 + 1] = v.y;
        }

        __syncthreads();   // new h + (maybe) new x tile visible
        p ^= 1;
    }
    // After 512 steps (even), final h is in hbuf[0].

    // Epilogue: out[row][p] = h[row] . W_out[p] + b_out[p]
    const int  pA   = cid;
    const int  pB   = 64 + cid;
    const bool hasB = (cid < 32);
    float accA[8], accB[8];
#pragma unroll
    for (int rr = 0; rr < 8; ++rr) { accA[rr] = 0.0f; accB[rr] = 0.0f; }

    for (int k = 0; k < H_DIM; k += 4) {
        float4 hv[8];
#pragma unroll
        for (int rr = 0; rr < 8; ++rr)
            hv[rr] = *(const float4*)&hbuf[0][myrow + rr][k];
        float wA[4], wB[4];
#pragma unroll
        for (int kk = 0; kk < 4; ++kk) {
            wA[kk] = TW ? Wout[(size_t)(k + kk) * P_DIM + pA]
                        : Wout[(size_t)pA * H_DIM + k + kk];
            wB[kk] = hasB ? (TW ? Wout[(size_t)(k + kk) * P_DIM + pB]
                                : Wout[(size_t)pB * H_DIM + k + kk])
                          : 0.0f;
        }
#pragma unroll
        for (int kk = 0; kk < 4; ++kk)
#pragma unroll
            for (int rr = 0; rr < 8; ++rr) {
                const float hvv = (&hv[rr].x)[kk];
                accA[rr] = fmaf(hvv, wA[kk], accA[rr]);
                accB[rr] = fmaf(hvv, wB[kk], accB[rr]);
            }
    }
    const float boA = b_out[pA];
    const float boB = hasB ? b_out[pB] : 0.0f;
#pragma unroll
    for (int rr = 0; rr < 8; ++rr) {
        const size_t orow = (size_t)(row0 + myrow + rr) * P_DIM;
        out[orow + pA] = accA[rr] + boA;
        if (hasB) out[orow + pB] = accB[rr] + boB;
    }
}

extern "C" void kernel_launch(void* const* d_in, const int* in_sizes, int n_in,
                              void* d_out, int out_size, void* d_ws, size_t ws_size,
                              hipStream_t stream) {
    const float* x     = (const float*)d_in[0];
    const float* W_ih  = (const float*)d_in[1];
    const float* W_hh  = (const float*)d_in[2];
    const float* b_ih  = (const float*)d_in[3];
    const float* b_hh  = (const float*)d_in[4];
    const float* W_out = (const float*)d_in[5];
    const float* b_out = (const float*)d_in[6];
    float* out = (float*)d_out;

    const size_t WT_elems  = (size_t)H_DIM * G3;     // 196608
    const size_t WoT_elems = (size_t)H_DIM * P_DIM;  // 24576
    const size_t need = (WT_elems + WoT_elems) * sizeof(float);

    if (ws_size >= need) {
        float* WT  = (float*)d_ws;
        float* WoT = WT + WT_elems;
        const int total = (int)(WT_elems + WoT_elems);
        transpose_weights<<<(total + 255) / 256, 256, 0, stream>>>(W_hh, W_out, WT, WoT);
        gru_persist<true><<<B_ROWS / TB, 256, 0, stream>>>(x, W_ih, WT, b_ih, b_hh,
                                                           WoT, b_out, out);
    } else {
        gru_persist<false><<<B_ROWS / TB, 256, 0, stream>>>(x, W_ih, W_hh, b_ih, b_hh,
                                                            W_out, b_out, out);
    }
}

// Round 3
// 11683.783 us; speedup vs baseline: 2.3987x; 1.7752x over previous
//
#include <hip/hip_runtime.h>
#include <math.h>

// Problem constants
#define B_ROWS 8192
#define S_LEN  512
#define H_DIM  256
#define G3     768          // 3*H
#define P_DIM  96
#define TB     32           // batch rows per block

typedef __attribute__((ext_vector_type(8))) short short8;   // 8 bf16 (4 VGPRs)
typedef __attribute__((ext_vector_type(4))) float floatx4;  // MFMA C/D frag

__device__ __forceinline__ float sigmoid_fast(float v) {
    return 1.0f / (1.0f + __expf(-v));
}
__device__ __forceinline__ float tanh_fast(float v) {
    return 1.0f - 2.0f / (__expf(2.0f * v) + 1.0f);
}
__device__ __forceinline__ unsigned short f32_bf16_rtn(float f) {
    unsigned int u = __float_as_uint(f);
    u += 0x7fffu + ((u >> 16) & 1u);   // round-to-nearest-even
    return (unsigned short)(u >> 16);
}
__device__ __forceinline__ float bf16_f32(unsigned short h) {
    return __uint_as_float(((unsigned int)h) << 16);
}

// -------- One-time weight pack: W_hh -> per-lane MFMA B-fragments (hi/lo bf16).
// B[k][n] = W_hh[n][k].  16x16x32 B-frag: lane holds B[n=lane&15][k=quad*8+j].
// Bpack[kc][gnt][lane][8] so a lane's 8 bf16 are one contiguous 16B load.
// Also WoT[k][p] = W_out[p][k] for the fp32 epilogue.
__global__ void pack_weights(const float* __restrict__ W_hh,
                             const float* __restrict__ W_out,
                             unsigned short* __restrict__ Bh,
                             unsigned short* __restrict__ Bl,
                             float* __restrict__ WoT) {
    const int j = blockIdx.x;    // gate col 0..767
    const int k = threadIdx.x;   // h idx   0..255
    const float wv = W_hh[j * H_DIM + k];
    const unsigned short hi = f32_bf16_rtn(wv);
    const unsigned short lo = f32_bf16_rtn(wv - bf16_f32(hi));
    const int idx = (((k >> 5) * 48 + (j >> 4)) * 64 +
                     ((j & 15) | (((k >> 3) & 3) << 4))) * 8 + (k & 7);
    Bh[idx] = hi;
    Bl[idx] = lo;
    if (j < P_DIM) WoT[k * P_DIM + j] = W_out[j * H_DIM + k];
}

// -------- Main persistent GRU kernel, split-bf16 MFMA.
// grid = 256 blocks (1/CU), block = 512 threads (8 waves, 2/SIMD).
// Wave w owns h-cols [32w,32w+32) for ALL 3 gates -> gate combine is in-register;
// h_old lives in C-frag registers across steps. h round-trips LDS only to be
// re-distributed as A-fragments (per-lane packed bf16 hi/lo).
__global__ __launch_bounds__(512, 2)
void gru_mfma(const float* __restrict__ x,
              const float* __restrict__ W_ih,
              const float* __restrict__ b_ih,
              const float* __restrict__ b_hh,
              const uint4* __restrict__ Bh,    // packed W_hh hi frags
              const uint4* __restrict__ Bl,    // packed W_hh lo frags
              const float* __restrict__ WoT,   // [256][96]
              const float* __restrict__ b_out,
              float* __restrict__ out) {
    __shared__ union {
        struct { short8 hi[16 * 64]; short8 lo[16 * 64]; } ap;  // A frags, 32 KiB
        float hfin[TB][H_DIM];                                  // epilogue h, 32 KiB
    } su;
    __shared__ float xtile[2][TB][16];   // 16-step x staging, double-buffered

    const int tid  = threadIdx.x;
    const int w    = tid >> 6;     // wave 0..7
    const int lane = tid & 63;
    const int q    = lane >> 4;    // quad
    const int c    = lane & 15;
    const int row0 = blockIdx.x * TB;

    // Per-thread gate params; col = 256*g + 32*w + 16*ht + c
    float wih[3][2], bcc[2][2], bihn[2], bhhn[2];
#pragma unroll
    for (int g = 0; g < 3; ++g)
#pragma unroll
        for (int ht = 0; ht < 2; ++ht) {
            const int col = g * H_DIM + w * 32 + ht * 16 + c;
            wih[g][ht] = W_ih[col];
            if (g < 2) {
                bcc[g][ht] = b_ih[col] + b_hh[col];
            } else {
                bihn[ht] = b_ih[col];
                bhhn[ht] = b_hh[col];
            }
        }

    // Zero A frags (h0 = 0) and stage x for t=0..15.
    for (int i = tid; i < 16 * 64 * 8 * 2; i += 512) ((short*)&su.ap)[i] = 0;
    {
        const int r = tid >> 4, t2 = tid & 15;
        xtile[0][r][t2] = x[(size_t)(row0 + r) * S_LEN + t2];
    }
    __syncthreads();

    // h_old in C-frag layout: element (mt,ht,reg) = h[4q+reg+16mt][32w+16ht+c]
    float h_own[2][2][4];
#pragma unroll
    for (int mt = 0; mt < 2; ++mt)
#pragma unroll
        for (int ht = 0; ht < 2; ++ht)
#pragma unroll
            for (int r = 0; r < 4; ++r) h_own[mt][ht][r] = 0.0f;

    for (int t = 0; t < S_LEN; ++t) {
        const int xb = (t >> 4) & 1;

        // x for my 8 rows (LDS broadcast)
        float xr[2][4];
#pragma unroll
        for (int mt = 0; mt < 2; ++mt)
#pragma unroll
            for (int r = 0; r < 4; ++r)
                xr[mt][r] = xtile[xb][q * 4 + r + 16 * mt][t & 15];

        // C frags [gate][mt][ht]; fold x-side pre-activation + bias into init.
        floatx4 acc[3][2][2];
#pragma unroll
        for (int mt = 0; mt < 2; ++mt)
#pragma unroll
            for (int ht = 0; ht < 2; ++ht)
#pragma unroll
                for (int r = 0; r < 4; ++r) {
                    acc[0][mt][ht][r] = fmaf(xr[mt][r], wih[0][ht], bcc[0][ht]);
                    acc[1][mt][ht][r] = fmaf(xr[mt][r], wih[1][ht], bcc[1][ht]);
                    acc[2][mt][ht][r] = bhhn[ht];
                }

        // K loop: 8 chunks of K=32.  Per chunk: A frags from LDS (b128,
        // conflict-free), B frags from global (16B/lane coalesced, L1/L2-hot),
        // 3 split-term MFMAs per tile.
        for (int kc = 0; kc < 8; ++kc) {
            short8 ah[2], al[2];
#pragma unroll
            for (int mt = 0; mt < 2; ++mt) {
                ah[mt] = su.ap.hi[(kc * 2 + mt) * 64 + lane];
                al[mt] = su.ap.lo[(kc * 2 + mt) * 64 + lane];
            }
#pragma unroll
            for (int g = 0; g < 3; ++g)
#pragma unroll
                for (int ht = 0; ht < 2; ++ht) {
                    const int tile = (kc * 48 + g * 16 + w * 2 + ht) * 64 + lane;
                    union { uint4 u; short8 s; } bh, bl;
                    bh.u = Bh[tile];
                    bl.u = Bl[tile];
#pragma unroll
                    for (int mt = 0; mt < 2; ++mt) {
                        acc[g][mt][ht] = __builtin_amdgcn_mfma_f32_16x16x32_bf16(
                            ah[mt], bh.s, acc[g][mt][ht], 0, 0, 0);
                        acc[g][mt][ht] = __builtin_amdgcn_mfma_f32_16x16x32_bf16(
                            al[mt], bh.s, acc[g][mt][ht], 0, 0, 0);
                        acc[g][mt][ht] = __builtin_amdgcn_mfma_f32_16x16x32_bf16(
                            ah[mt], bl.s, acc[g][mt][ht], 0, 0, 0);
                    }
                }
        }
        __syncthreads();   // all A-frag reads of step t complete

        // Gates + h update (in-register), then scatter next step's A frags.
        unsigned short* aph = (unsigned short*)su.ap.hi;
        unsigned short* apl = (unsigned short*)su.ap.lo;
#pragma unroll
        for (int mt = 0; mt < 2; ++mt)
#pragma unroll
            for (int ht = 0; ht < 2; ++ht)
#pragma unroll
                for (int r = 0; r < 4; ++r) {
                    const float rr  = sigmoid_fast(acc[0][mt][ht][r]);
                    const float zz  = sigmoid_fast(acc[1][mt][ht][r]);
                    const float inn = fmaf(xr[mt][r], wih[2][ht], bihn[ht]);
                    const float nn  = tanh_fast(fmaf(rr, acc[2][mt][ht][r], inn));
                    const float hv  = (1.0f - zz) * nn + zz * h_own[mt][ht][r];
                    h_own[mt][ht][r] = hv;
                    const unsigned short hi = f32_bf16_rtn(hv);
                    const unsigned short lo = f32_bf16_rtn(hv - bf16_f32(hi));
                    // dest: kc=w, k_local=16ht+c, m=4q+r+16mt
                    const int dlane = (q * 4 + r) | ((2 * ht + (c >> 3)) << 4);
                    const int idx   = ((w * 2 + mt) * 64 + dlane) * 8 + (c & 7);
                    aph[idx] = hi;
                    apl[idx] = lo;
                }

        // Re-stage x for the next 16 steps.
        if ((t & 15) == 15 && t != S_LEN - 1) {
            const int r = tid >> 4, t2 = tid & 15;
            xtile[xb ^ 1][r][t2] = x[(size_t)(row0 + r) * S_LEN + (t + 1) + t2];
        }
        __syncthreads();   // new A frags + x tile visible
    }

    // -------- Epilogue: dump final h (fp32, from registers) and project.
#pragma unroll
    for (int mt = 0; mt < 2; ++mt)
#pragma unroll
        for (int ht = 0; ht < 2; ++ht)
#pragma unroll
            for (int r = 0; r < 4; ++r) {
                const int m = q * 4 + r + 16 * mt;
                const int k = w * 32 + ht * 16 + c;
                su.hfin[m][k] = h_own[mt][ht][r];
            }
    __syncthreads();

    if (tid < 256) {
        const int cid   = tid & 63;
        const int rid   = tid >> 6;
        const int myrow = rid * 8;
        const int pA    = cid;
        const int pB    = 64 + cid;
        const bool hasB = (cid < 32);
        float accA[8], accB[8];
#pragma unroll
        for (int rr = 0; rr < 8; ++rr) { accA[rr] = 0.0f; accB[rr] = 0.0f; }

        for (int k = 0; k < H_DIM; k += 4) {
            float4 hv[8];
#pragma unroll
            for (int rr = 0; rr < 8; ++rr)
                hv[rr] = *(const float4*)&su.hfin[myrow + rr][k];
            float wA[4], wB[4];
#pragma unroll
            for (int kk = 0; kk < 4; ++kk) {
                wA[kk] = WoT[(size_t)(k + kk) * P_DIM + pA];
                wB[kk] = hasB ? WoT[(size_t)(k + kk) * P_DIM + pB] : 0.0f;
            }
#pragma unroll
            for (int kk = 0; kk < 4; ++kk)
#pragma unroll
                for (int rr = 0; rr < 8; ++rr) {
                    const float hvv = (&hv[rr].x)[kk];
                    accA[rr] = fmaf(hvv, wA[kk], accA[rr]);
                    accB[rr] = fmaf(hvv, wB[kk], accB[rr]);
                }
        }
        const float boA = b_out[pA];
        const float boB = hasB ? b_out[pB] : 0.0f;
#pragma unroll
        for (int rr = 0; rr < 8; ++rr) {
            const size_t orow = (size_t)(row0 + myrow + rr) * P_DIM;
            out[orow + pA] = accA[rr] + boA;
            if (hasB) out[orow + pB] = accB[rr] + boB;
        }
    }
}

// -------- fp32 fallback (round-2 kernel, untransposed weights) — used only if
// ws_size is too small for the packed weights. Correctness over speed.
__global__ __launch_bounds__(256, 1)
void gru_fallback(const float* __restrict__ x,
                  const float* __restrict__ W_ih,
                  const float* __restrict__ Whh,
                  const float* __restrict__ b_ih,
                  const float* __restrict__ b_hh,
                  const float* __restrict__ Wout,
                  const float* __restrict__ b_out,
                  float* __restrict__ out) {
    __shared__ float hbuf[2][TB][H_DIM];

    const int tid   = threadIdx.x;
    const int cid   = tid & 63;
    const int rid   = tid >> 6;
    const int row0  = blockIdx.x * TB;
    const int myrow = rid * 8;
    const int c0    = cid * 4;

    float wih[3][4], bc[2][4], bihn[4], bhhn[4];
#pragma unroll
    for (int cc = 0; cc < 4; ++cc) {
        const int j = c0 + cc;
        wih[0][cc] = W_ih[j];
        wih[1][cc] = W_ih[H_DIM + j];
        wih[2][cc] = W_ih[2 * H_DIM + j];
        bc[0][cc]  = b_ih[j] + b_hh[j];
        bc[1][cc]  = b_ih[H_DIM + j] + b_hh[H_DIM + j];
        bihn[cc]   = b_ih[2 * H_DIM + j];
        bhhn[cc]   = b_hh[2 * H_DIM + j];
    }
    for (int i = tid; i < TB * H_DIM; i += 256) (&hbuf[0][0][0])[i] = 0.0f;
    float h_own[8][4];
#pragma unroll
    for (int rr = 0; rr < 8; ++rr)
#pragma unroll
        for (int cc = 0; cc < 4; ++cc) h_own[rr][cc] = 0.0f;
    __syncthreads();

    int p = 0;
    for (int t = 0; t < S_LEN; ++t) {
        float xv[8];
#pragma unroll
        for (int rr = 0; rr < 8; ++rr)
            xv[rr] = x[(size_t)(row0 + myrow + rr) * S_LEN + t];

        float acc[3][8][4];
#pragma unroll
        for (int rr = 0; rr < 8; ++rr)
#pragma unroll
            for (int cc = 0; cc < 4; ++cc) {
                acc[0][rr][cc] = fmaf(xv[rr], wih[0][cc], bc[0][cc]);
                acc[1][rr][cc] = fmaf(xv[rr], wih[1][cc], bc[1][cc]);
                acc[2][rr][cc] = bhhn[cc];
            }
        const float* hb = &hbuf[p][0][0];
        for (int k = 0; k < H_DIM; k += 4) {
            float4 hv[8];
#pragma unroll
            for (int rr = 0; rr < 8; ++rr)
                hv[rr] = *(const float4*)(hb + (myrow + rr) * H_DIM + k);
#pragma unroll
            for (int g = 0; g < 3; ++g)
#pragma unroll
                for (int kk = 0; kk < 4; ++kk) {
                    float wrow[4];
#pragma unroll
                    for (int cc = 0; cc < 4; ++cc)
                        wrow[cc] = Whh[(size_t)(g * H_DIM + c0 + cc) * H_DIM + k + kk];
#pragma unroll
                    for (int rr = 0; rr < 8; ++rr) {
                        const float hvv = (&hv[rr].x)[kk];
#pragma unroll
                        for (int cc = 0; cc < 4; ++cc)
                            acc[g][rr][cc] = fmaf(hvv, wrow[cc], acc[g][rr][cc]);
                    }
                }
        }
#pragma unroll
        for (int rr = 0; rr < 8; ++rr) {
            float4 hnew;
#pragma unroll
            for (int cc = 0; cc < 4; ++cc) {
                const float r_  = sigmoid_fast(acc[0][rr][cc]);
                const float z_  = sigmoid_fast(acc[1][rr][cc]);
                const float i_n = fmaf(xv[rr], wih[2][cc], bihn[cc]);
                const float n_  = tanh_fast(fmaf(r_, acc[2][rr][cc], i_n));
                const float hv2 = (1.0f - z_) * n_ + z_ * h_own[rr][cc];
                h_own[rr][cc] = hv2;
                (&hnew.x)[cc] = hv2;
            }
            *(float4*)&hbuf[1 - p][myrow + rr][c0] = hnew;
        }
        __syncthreads();
        p ^= 1;
    }

    const int  pA   = cid;
    const int  pB   = 64 + cid;
    const bool hasB = (cid < 32);
    float accA[8], accB[8];
#pragma unroll
    for (int rr = 0; rr < 8; ++rr) { accA[rr] = 0.0f; accB[rr] = 0.0f; }
    for (int k = 0; k < H_DIM; k += 4) {
        float4 hv[8];
#pragma unroll
        for (int rr = 0; rr < 8; ++rr)
            hv[rr] = *(const float4*)&hbuf[p][myrow + rr][k];
        float wA[4], wB[4];
#pragma unroll
        for (int kk = 0; kk < 4; ++kk) {
            wA[kk] = Wout[(size_t)pA * H_DIM + k + kk];
            wB[kk] = hasB ? Wout[(size_t)pB * H_DIM + k + kk] : 0.0f;
        }
#pragma unroll
        for (int kk = 0; kk < 4; ++kk)
#pragma unroll
            for (int rr = 0; rr < 8; ++rr) {
                const float hvv = (&hv[rr].x)[kk];
                accA[rr] = fmaf(hvv, wA[kk], accA[rr]);
                accB[rr] = fmaf(hvv, wB[kk], accB[rr]);
            }
    }
    const float boA = b_out[pA];
    const float boB = hasB ? b_out[pB] : 0.0f;
#pragma unroll
    for (int rr = 0; rr < 8; ++rr) {
        const size_t orow = (size_t)(row0 + myrow + rr) * P_DIM;
        out[orow + pA] = accA[rr] + boA;
        if (hasB) out[orow + pB] = accB[rr] + boB;
    }
}

extern "C" void kernel_launch(void* const* d_in, const int* in_sizes, int n_in,
                              void* d_out, int out_size, void* d_ws, size_t ws_size,
                              hipStream_t stream) {
    const float* x     = (const float*)d_in[0];
    const float* W_ih  = (const float*)d_in[1];
    const float* W_hh  = (const float*)d_in[2];
    const float* b_ih  = (const float*)d_in[3];
    const float* b_hh  = (const float*)d_in[4];
    const float* W_out = (const float*)d_in[5];
    const float* b_out = (const float*)d_in[6];
    float* out = (float*)d_out;

    const size_t bpack_elems = 8 * 48 * 64 * 8;          // 196608 bf16 per matrix
    const size_t wot_elems   = (size_t)H_DIM * P_DIM;    // 24576 fp32
    const size_t need = bpack_elems * 2 * sizeof(unsigned short) * 2 +
                        wot_elems * sizeof(float);       // 884736 B

    if (ws_size >= need) {
        unsigned short* Bh = (unsigned short*)d_ws;
        unsigned short* Bl = Bh + bpack_elems * 2;       // hi is uint4-aligned block
        float* WoT = (float*)(Bl + bpack_elems * 2);
        // NOTE: Bh/Bl each occupy bpack_elems ushorts; the *2 spacing keeps
        // both 16B-aligned with slack (ws budget covers it: 2*2*bpack = 786432).
        pack_weights<<<G3, H_DIM, 0, stream>>>(W_hh, W_out, Bh, Bl, WoT);
        gru_mfma<<<B_ROWS / TB, 512, 0, stream>>>(x, W_ih, b_ih, b_hh,
                                                  (const uint4*)Bh, (const uint4*)Bl,
                                                  WoT, b_out, out);
    } else {
        gru_fallback<<<B_ROWS / TB, 256, 0, stream>>>(x, W_ih, W_hh, b_ih, b_hh,
                                                      W_out, b_out, out);
    }
}

// Round 4
// 5778.528 us; speedup vs baseline: 4.8499x; 2.0219x over previous
//
#include <hip/hip_runtime.h>
#include <math.h>

// Problem constants
#define B_ROWS 8192
#define S_LEN  512
#define H_DIM  256
#define G3     768          // 3*H
#define P_DIM  96
#define TB     32           // batch rows per block

typedef __attribute__((ext_vector_type(8))) short short8;   // 8 bf16 (4 VGPRs)
typedef __attribute__((ext_vector_type(4))) float floatx4;  // MFMA C/D frag

__device__ __forceinline__ float sigmoid_fast(float v) {
    return 1.0f / (1.0f + __expf(-v));
}
__device__ __forceinline__ float tanh_fast(float v) {
    return 1.0f - 2.0f / (__expf(2.0f * v) + 1.0f);
}
__device__ __forceinline__ unsigned short f32_bf16_rtn(float f) {
    unsigned int u = __float_as_uint(f);
    u += 0x7fffu + ((u >> 16) & 1u);   // round-to-nearest-even
    return (unsigned short)(u >> 16);
}
__device__ __forceinline__ float bf16_f32(unsigned short h) {
    return __uint_as_float(((unsigned int)h) << 16);
}
// Involutive 6-bit lane rotation: spreads scatter dest-lanes across bank groups.
__device__ __forceinline__ int rot3(int l) { return ((l << 3) | (l >> 3)) & 63; }

// -------- One-time weight pack: W_hh -> per-lane MFMA B-fragments (hi/lo bf16).
// B[k][n] = W_hh[n][k].  16x16x32 B-frag: lane holds B[n=lane&15][k=quad*8+j].
// Tile index = (k>>5)*48 + (j>>4); lane = (j&15) | (((k>>3)&3)<<4); short = k&7.
// Also WoT[k][p] = W_out[p][k]; also zeroes the phase-sync counter.
__global__ void pack_weights(const float* __restrict__ W_hh,
                             const float* __restrict__ W_out,
                             unsigned short* __restrict__ Bh,
                             unsigned short* __restrict__ Bl,
                             float* __restrict__ WoT,
                             unsigned int* __restrict__ ctr) {
    const int j = blockIdx.x;    // gate col 0..767
    const int k = threadIdx.x;   // h idx   0..255
    const float wv = W_hh[j * H_DIM + k];
    const unsigned short hi = f32_bf16_rtn(wv);
    const unsigned short lo = f32_bf16_rtn(wv - bf16_f32(hi));
    const int idx = (((k >> 5) * 48 + (j >> 4)) * 64 +
                     ((j & 15) | (((k >> 3) & 3) << 4))) * 8 + (k & 7);
    Bh[idx] = hi;
    Bl[idx] = lo;
    if (j < P_DIM) WoT[k * P_DIM + j] = W_out[j * H_DIM + k];
    if (j == 0 && k == 0) *ctr = 0u;   // d_ws is re-poisoned every launch
}

// LDS layout (148 KiB total):
//   [0,       65536)  A-fragments, double-buffered: buf*32768 + m(hi/lo)*16384
//                     + chunk(kc*2+mt)*1024 + slot*16 + short*2  (slot = rot3'd)
//   [65536,   69632)  xtile[2][32][16] fp32
//   [69632,  151552)  W cache: 80 tiles x 1 KiB
//                     slots 0..47  = kc=6 lo  (index g*16 + w*2 + ht)
//                     slots 48..79 = kc=5 hi, g<2 (index g*16 + w*2 + ht)
#define A_OFF   0
#define X_OFF   65536
#define W_OFF   69632
#define LDS_SZ  151552

__device__ __forceinline__ void mfma3(floatx4& c0, floatx4& c1,
                                      const short8& ah0, const short8& ah1,
                                      const short8& al0, const short8& al1,
                                      const short8& bh, const short8& bl) {
    c0 = __builtin_amdgcn_mfma_f32_16x16x32_bf16(ah0, bh, c0, 0, 0, 0);
    c1 = __builtin_amdgcn_mfma_f32_16x16x32_bf16(ah1, bh, c1, 0, 0, 0);
    c0 = __builtin_amdgcn_mfma_f32_16x16x32_bf16(al0, bh, c0, 0, 0, 0);
    c1 = __builtin_amdgcn_mfma_f32_16x16x32_bf16(al1, bh, c1, 0, 0, 0);
    c0 = __builtin_amdgcn_mfma_f32_16x16x32_bf16(ah0, bl, c0, 0, 0, 0);
    c1 = __builtin_amdgcn_mfma_f32_16x16x32_bf16(ah1, bl, c1, 0, 0, 0);
}

// Main persistent GRU kernel: split-bf16 MFMA + partial weight residency.
// grid = 256 (1 block/CU, forced by 148 KiB LDS), block = 512 (8 waves).
__global__ __launch_bounds__(512, 2)
void gru_mfma(const float* __restrict__ x,
              const float* __restrict__ W_ih,
              const float* __restrict__ b_ih,
              const float* __restrict__ b_hh,
              const unsigned short* __restrict__ Bh,
              const unsigned short* __restrict__ Bl,
              const float* __restrict__ WoT,   // [256][96]
              const float* __restrict__ b_out,
              float* __restrict__ out,
              unsigned int* __restrict__ ctr) {
    __shared__ __align__(16) char smem[LDS_SZ];

    const int tid  = threadIdx.x;
    const int w    = tid >> 6;     // wave 0..7
    const int lane = tid & 63;
    const int q    = lane >> 4;    // quad
    const int c    = lane & 15;
    const int row0 = blockIdx.x * TB;

    // Per-thread gate params; col = 256*g + 32*w + 16*ht + c
    float wih[3][2], bcc[2][2], bihn[2], bhhn[2];
#pragma unroll
    for (int g = 0; g < 3; ++g)
#pragma unroll
        for (int ht = 0; ht < 2; ++ht) {
            const int col = g * H_DIM + w * 32 + ht * 16 + c;
            wih[g][ht] = W_ih[col];
            if (g < 2) {
                bcc[g][ht] = b_ih[col] + b_hh[col];
            } else {
                bihn[ht] = b_ih[col];
                bhhn[ht] = b_hh[col];
            }
        }

    // Streamed-tile base pointers (per wave/lane), gh = g*2 + ht.
    const unsigned short* pbh[6];
    const unsigned short* pbl[6];
#pragma unroll
    for (int gh = 0; gh < 6; ++gh) {
        const size_t toff = (size_t)((gh >> 1) * 16 + w * 2 + (gh & 1)) * 512 + lane * 8;
        pbh[gh] = Bh + toff;
        pbl[gh] = Bl + toff;
    }

    union U16 { uint4 u; short8 s; };

    // Register-resident weight tiles: kc=7 hi+lo, kc=6 hi.  (72 VGPRs)
    short8 r7h[6], r7l[6], r6h[6];
#pragma unroll
    for (int gh = 0; gh < 6; ++gh) {
        U16 a, b, d;
        a.u = *(const uint4*)(pbh[gh] + 7 * 24576);
        b.u = *(const uint4*)(pbl[gh] + 7 * 24576);
        d.u = *(const uint4*)(pbh[gh] + 6 * 24576);
        r7h[gh] = a.s; r7l[gh] = b.s; r6h[gh] = d.s;
    }

    // LDS weight cache staging: 80 tiles (kc=6 lo: Bl tiles 288..335;
    // kc=5 hi g<2: Bh tiles 240..271).
    for (int i = tid; i < 80 * 64; i += 512) {
        const int slot = i >> 6, l16 = i & 63;
        const unsigned short* src = (slot < 48)
            ? (Bl + (size_t)(288 + slot) * 512 + l16 * 8)
            : (Bh + (size_t)(240 + slot - 48) * 512 + l16 * 8);
        *(uint4*)(smem + W_OFF + slot * 1024 + l16 * 16) = *(const uint4*)src;
    }

    // Zero both A-frag buffers (h0 = 0) and stage x for t=0..15.
    for (int i = tid; i < 16384; i += 512) ((int*)(smem + A_OFF))[i] = 0;
    float* xt = (float*)(smem + X_OFF);
    {
        const int r = tid >> 4, t2 = tid & 15;
        xt[r * 16 + t2] = x[(size_t)(row0 + r) * S_LEN + t2];
    }
    __syncthreads();

    // h_old in C-frag layout: element (mt,ht,reg) = h[4q+reg+16mt][32w+16ht+c]
    float h_own[2][2][4];
#pragma unroll
    for (int mt = 0; mt < 2; ++mt)
#pragma unroll
        for (int ht = 0; ht < 2; ++ht)
#pragma unroll
            for (int r = 0; r < 4; ++r) h_own[mt][ht][r] = 0.0f;

    const int rl = rot3(lane);

    for (int t = 0; t < S_LEN; ++t) {
        const int cur = t & 1, nxt = cur ^ 1;
        const char* Ah = smem + A_OFF + cur * 32768;
        const char* Al = Ah + 16384;

        // x for my 8 rows (LDS broadcast)
        float xr[2][4];
#pragma unroll
        for (int mt = 0; mt < 2; ++mt)
#pragma unroll
            for (int r = 0; r < 4; ++r)
                xr[mt][r] = xt[(((t >> 4) & 1) * 32 + q * 4 + r + 16 * mt) * 16 + (t & 15)];

        // C frags [gate][mt][ht]; fold x-side pre-activation + bias into init.
        floatx4 acc[3][2][2];
#pragma unroll
        for (int mt = 0; mt < 2; ++mt)
#pragma unroll
            for (int ht = 0; ht < 2; ++ht)
#pragma unroll
                for (int r = 0; r < 4; ++r) {
                    acc[0][mt][ht][r] = fmaf(xr[mt][r], wih[0][ht], bcc[0][ht]);
                    acc[1][mt][ht][r] = fmaf(xr[mt][r], wih[1][ht], bcc[1][ht]);
                    acc[2][mt][ht][r] = bhhn[ht];
                }

        // ---- kc = 0..4: fully streamed from L2 ----
#pragma unroll 1
        for (int kc = 0; kc < 5; ++kc) {
            short8 ah[2], al[2];
#pragma unroll
            for (int mt = 0; mt < 2; ++mt) {
                ah[mt] = *(const short8*)(Ah + (kc * 2 + mt) * 1024 + rl * 16);
                al[mt] = *(const short8*)(Al + (kc * 2 + mt) * 1024 + rl * 16);
            }
#pragma unroll
            for (int gh = 0; gh < 6; ++gh) {
                U16 bh, bl;
                bh.u = *(const uint4*)(pbh[gh] + (size_t)kc * 24576);
                bl.u = *(const uint4*)(pbl[gh] + (size_t)kc * 24576);
                mfma3(acc[gh >> 1][0][gh & 1], acc[gh >> 1][1][gh & 1],
                      ah[0], ah[1], al[0], al[1], bh.s, bl.s);
            }
        }

        // ---- kc = 5: hi g<2 from LDS, hi g=2 + all lo streamed ----
        {
            short8 ah[2], al[2];
#pragma unroll
            for (int mt = 0; mt < 2; ++mt) {
                ah[mt] = *(const short8*)(Ah + (10 + mt) * 1024 + rl * 16);
                al[mt] = *(const short8*)(Al + (10 + mt) * 1024 + rl * 16);
            }
#pragma unroll
            for (int gh = 0; gh < 6; ++gh) {
                U16 bh, bl;
                if (gh < 4) {
                    const int slot = 48 + (gh >> 1) * 16 + w * 2 + (gh & 1);
                    bh.s = *(const short8*)(smem + W_OFF + slot * 1024 + lane * 16);
                } else {
                    bh.u = *(const uint4*)(pbh[gh] + (size_t)5 * 24576);
                }
                bl.u = *(const uint4*)(pbl[gh] + (size_t)5 * 24576);
                mfma3(acc[gh >> 1][0][gh & 1], acc[gh >> 1][1][gh & 1],
                      ah[0], ah[1], al[0], al[1], bh.s, bl.s);
            }
        }

        // ---- kc = 6: hi from regs, lo from LDS ----
        {
            short8 ah[2], al[2];
#pragma unroll
            for (int mt = 0; mt < 2; ++mt) {
                ah[mt] = *(const short8*)(Ah + (12 + mt) * 1024 + rl * 16);
                al[mt] = *(const short8*)(Al + (12 + mt) * 1024 + rl * 16);
            }
#pragma unroll
            for (int gh = 0; gh < 6; ++gh) {
                const int slot = (gh >> 1) * 16 + w * 2 + (gh & 1);
                short8 bl = *(const short8*)(smem + W_OFF + slot * 1024 + lane * 16);
                mfma3(acc[gh >> 1][0][gh & 1], acc[gh >> 1][1][gh & 1],
                      ah[0], ah[1], al[0], al[1], r6h[gh], bl);
            }
        }

        // ---- kc = 7: fully register-resident ----
        {
            short8 ah[2], al[2];
#pragma unroll
            for (int mt = 0; mt < 2; ++mt) {
                ah[mt] = *(const short8*)(Ah + (14 + mt) * 1024 + rl * 16);
                al[mt] = *(const short8*)(Al + (14 + mt) * 1024 + rl * 16);
            }
#pragma unroll
            for (int gh = 0; gh < 6; ++gh)
                mfma3(acc[gh >> 1][0][gh & 1], acc[gh >> 1][1][gh & 1],
                      ah[0], ah[1], al[0], al[1], r7h[gh], r7l[gh]);
        }

        // Gates + h update (in-register); scatter next A-frags (rot3-swizzled).
        char* Anx = smem + A_OFF + nxt * 32768;
#pragma unroll
        for (int mt = 0; mt < 2; ++mt) {
            char* chh = Anx + (w * 2 + mt) * 1024;          // hi chunk (kc=w)
            char* cll = chh + 16384;                        // lo chunk
#pragma unroll
            for (int ht = 0; ht < 2; ++ht)
#pragma unroll
                for (int r = 0; r < 4; ++r) {
                    const float rr  = sigmoid_fast(acc[0][mt][ht][r]);
                    const float zz  = sigmoid_fast(acc[1][mt][ht][r]);
                    const float inn = fmaf(xr[mt][r], wih[2][ht], bihn[ht]);
                    const float nn  = tanh_fast(fmaf(rr, acc[2][mt][ht][r], inn));
                    const float hv  = (1.0f - zz) * nn + zz * h_own[mt][ht][r];
                    h_own[mt][ht][r] = hv;
                    const unsigned short hi = f32_bf16_rtn(hv);
                    const unsigned short lo = f32_bf16_rtn(hv - bf16_f32(hi));
                    const int d    = (q * 4 + r) | ((2 * ht + (c >> 3)) << 4);
                    const int off  = rot3(d) * 16 + (c & 7) * 2;
                    *(unsigned short*)(chh + off) = hi;
                    *(unsigned short*)(cll + off) = lo;
                }
        }

        // Re-stage x for the next 16 steps (into the idle x buffer).
        const bool tick = ((t & 15) == 15) && (t != S_LEN - 1);
        if (tick) {
            const int r = tid >> 4, t2 = tid & 15;
            xt[((((t + 1) >> 4) & 1) * 32 + r) * 16 + t2] =
                x[(size_t)(row0 + r) * S_LEN + (t + 1) + t2];
        }
        __syncthreads();   // single barrier: next A-frags + x tile visible

        // Phase-alignment heartbeat every 16 steps: keeps all 256 blocks'
        // weight streams in phase so the per-XCD L2 working set stays hot.
        // Pure timing hint — bounded spin, no data dependency, no fences.
        if (tick) {
            if (tid == 0) {
                const unsigned int tgt = 256u * (unsigned)((t >> 4) + 1);
                atomicAdd(ctr, 1u);
                for (int spin = 0; spin < (1 << 17); ++spin) {
                    if (__hip_atomic_load(ctr, __ATOMIC_RELAXED,
                                          __HIP_MEMORY_SCOPE_AGENT) >= tgt) break;
                    __builtin_amdgcn_s_sleep(4);
                }
            }
            __syncthreads();
        }
    }

    // -------- Epilogue: dump final h (fp32, from registers) and project.
    float* hfin = (float*)(smem);   // reuse A region: [32][256]
#pragma unroll
    for (int mt = 0; mt < 2; ++mt)
#pragma unroll
        for (int ht = 0; ht < 2; ++ht)
#pragma unroll
            for (int r = 0; r < 4; ++r) {
                const int m = q * 4 + r + 16 * mt;
                const int k = w * 32 + ht * 16 + c;
                hfin[m * H_DIM + k] = h_own[mt][ht][r];
            }
    __syncthreads();

    if (tid < 256) {
        const int cid   = tid & 63;
        const int rid   = tid >> 6;
        const int myrow = rid * 8;
        const int pA    = cid;
        const int pB    = 64 + cid;
        const bool hasB = (cid < 32);
        float accA[8], accB[8];
#pragma unroll
        for (int rr = 0; rr < 8; ++rr) { accA[rr] = 0.0f; accB[rr] = 0.0f; }

        for (int k = 0; k < H_DIM; k += 4) {
            float4 hv[8];
#pragma unroll
            for (int rr = 0; rr < 8; ++rr)
                hv[rr] = *(const float4*)&hfin[(myrow + rr) * H_DIM + k];
            float wA[4], wB[4];
#pragma unroll
            for (int kk = 0; kk < 4; ++kk) {
                wA[kk] = WoT[(size_t)(k + kk) * P_DIM + pA];
                wB[kk] = hasB ? WoT[(size_t)(k + kk) * P_DIM + pB] : 0.0f;
            }
#pragma unroll
            for (int kk = 0; kk < 4; ++kk)
#pragma unroll
                for (int rr = 0; rr < 8; ++rr) {
                    const float hvv = (&hv[rr].x)[kk];
                    accA[rr] = fmaf(hvv, wA[kk], accA[rr]);
                    accB[rr] = fmaf(hvv, wB[kk], accB[rr]);
                }
        }
        const float boA = b_out[pA];
        const float boB = hasB ? b_out[pB] : 0.0f;
#pragma unroll
        for (int rr = 0; rr < 8; ++rr) {
            const size_t orow = (size_t)(row0 + myrow + rr) * P_DIM;
            out[orow + pA] = accA[rr] + boA;
            if (hasB) out[orow + pB] = accB[rr] + boB;
        }
    }
}

// -------- fp32 fallback — used only if ws_size is too small.
__global__ __launch_bounds__(256, 1)
void gru_fallback(const float* __restrict__ x,
                  const float* __restrict__ W_ih,
                  const float* __restrict__ Whh,
                  const float* __restrict__ b_ih,
                  const float* __restrict__ b_hh,
                  const float* __restrict__ Wout,
                  const float* __restrict__ b_out,
                  float* __restrict__ out) {
    __shared__ float hbuf[2][TB][H_DIM];

    const int tid   = threadIdx.x;
    const int cid   = tid & 63;
    const int rid   = tid >> 6;
    const int row0  = blockIdx.x * TB;
    const int myrow = rid * 8;
    const int c0    = cid * 4;

    float wih[3][4], bc[2][4], bihn[4], bhhn[4];
#pragma unroll
    for (int cc = 0; cc < 4; ++cc) {
        const int j = c0 + cc;
        wih[0][cc] = W_ih[j];
        wih[1][cc] = W_ih[H_DIM + j];
        wih[2][cc] = W_ih[2 * H_DIM + j];
        bc[0][cc]  = b_ih[j] + b_hh[j];
        bc[1][cc]  = b_ih[H_DIM + j] + b_hh[H_DIM + j];
        bihn[cc]   = b_ih[2 * H_DIM + j];
        bhhn[cc]   = b_hh[2 * H_DIM + j];
    }
    for (int i = tid; i < TB * H_DIM; i += 256) (&hbuf[0][0][0])[i] = 0.0f;
    float h_own[8][4];
#pragma unroll
    for (int rr = 0; rr < 8; ++rr)
#pragma unroll
        for (int cc = 0; cc < 4; ++cc) h_own[rr][cc] = 0.0f;
    __syncthreads();

    int p = 0;
    for (int t = 0; t < S_LEN; ++t) {
        float xv[8];
#pragma unroll
        for (int rr = 0; rr < 8; ++rr)
            xv[rr] = x[(size_t)(row0 + myrow + rr) * S_LEN + t];

        float acc[3][8][4];
#pragma unroll
        for (int rr = 0; rr < 8; ++rr)
#pragma unroll
            for (int cc = 0; cc < 4; ++cc) {
                acc[0][rr][cc] = fmaf(xv[rr], wih[0][cc], bc[0][cc]);
                acc[1][rr][cc] = fmaf(xv[rr], wih[1][cc], bc[1][cc]);
                acc[2][rr][cc] = bhhn[cc];
            }
        const float* hb = &hbuf[p][0][0];
        for (int k = 0; k < H_DIM; k += 4) {
            float4 hv[8];
#pragma unroll
            for (int rr = 0; rr < 8; ++rr)
                hv[rr] = *(const float4*)(hb + (myrow + rr) * H_DIM + k);
#pragma unroll
            for (int g = 0; g < 3; ++g)
#pragma unroll
                for (int kk = 0; kk < 4; ++kk) {
                    float wrow[4];
#pragma unroll
                    for (int cc = 0; cc < 4; ++cc)
                        wrow[cc] = Whh[(size_t)(g * H_DIM + c0 + cc) * H_DIM + k + kk];
#pragma unroll
                    for (int rr = 0; rr < 8; ++rr) {
                        const float hvv = (&hv[rr].x)[kk];
#pragma unroll
                        for (int cc = 0; cc < 4; ++cc)
                            acc[g][rr][cc] = fmaf(hvv, wrow[cc], acc[g][rr][cc]);
                    }
                }
        }
#pragma unroll
        for (int rr = 0; rr < 8; ++rr) {
            float4 hnew;
#pragma unroll
            for (int cc = 0; cc < 4; ++cc) {
                const float r_  = sigmoid_fast(acc[0][rr][cc]);
                const float z_  = sigmoid_fast(acc[1][rr][cc]);
                const float i_n = fmaf(xv[rr], wih[2][cc], bihn[cc]);
                const float n_  = tanh_fast(fmaf(r_, acc[2][rr][cc], i_n));
                const float hv2 = (1.0f - z_) * n_ + z_ * h_own[rr][cc];
                h_own[rr][cc] = hv2;
                (&hnew.x)[cc] = hv2;
            }
            *(float4*)&hbuf[1 - p][myrow + rr][c0] = hnew;
        }
        __syncthreads();
        p ^= 1;
    }

    const int  pA   = cid;
    const int  pB   = 64 + cid;
    const bool hasB = (cid < 32);
    float accA[8], accB[8];
#pragma unroll
    for (int rr = 0; rr < 8; ++rr) { accA[rr] = 0.0f; accB[rr] = 0.0f; }
    for (int k = 0; k < H_DIM; k += 4) {
        float4 hv[8];
#pragma unroll
        for (int rr = 0; rr < 8; ++rr)
            hv[rr] = *(const float4*)&hbuf[p][myrow + rr][k];
        float wA[4], wB[4];
#pragma unroll
        for (int kk = 0; kk < 4; ++kk) {
            wA[kk] = Wout[(size_t)pA * H_DIM + k + kk];
            wB[kk] = hasB ? Wout[(size_t)pB * H_DIM + k + kk] : 0.0f;
        }
#pragma unroll
        for (int kk = 0; kk < 4; ++kk)
#pragma unroll
            for (int rr = 0; rr < 8; ++rr) {
                const float hvv = (&hv[rr].x)[kk];
                accA[rr] = fmaf(hvv, wA[kk], accA[rr]);
                accB[rr] = fmaf(hvv, wB[kk], accB[rr]);
            }
    }
    const float boA = b_out[pA];
    const float boB = hasB ? b_out[pB] : 0.0f;
#pragma unroll
    for (int rr = 0; rr < 8; ++rr) {
        const size_t orow = (size_t)(row0 + myrow + rr) * P_DIM;
        out[orow + pA] = accA[rr] + boA;
        if (hasB) out[orow + pB] = accB[rr] + boB;
    }
}

extern "C" void kernel_launch(void* const* d_in, const int* in_sizes, int n_in,
                              void* d_out, int out_size, void* d_ws, size_t ws_size,
                              hipStream_t stream) {
    const float* x     = (const float*)d_in[0];
    const float* W_ih  = (const float*)d_in[1];
    const float* W_hh  = (const float*)d_in[2];
    const float* b_ih  = (const float*)d_in[3];
    const float* b_hh  = (const float*)d_in[4];
    const float* W_out = (const float*)d_in[5];
    const float* b_out = (const float*)d_in[6];
    float* out = (float*)d_out;

    const size_t bpack_elems = 8 * 48 * 64 * 8;          // 196608 bf16 per matrix
    const size_t wot_elems   = (size_t)H_DIM * P_DIM;    // 24576 fp32
    const size_t ctr_off = bpack_elems * 2 * sizeof(unsigned short) * 2 +
                           wot_elems * sizeof(float);    // 1671168 B (16-aligned)
    const size_t need = ctr_off + sizeof(unsigned int);

    if (ws_size >= need) {
        unsigned short* Bh = (unsigned short*)d_ws;
        unsigned short* Bl = Bh + bpack_elems * 2;
        float* WoT = (float*)(Bl + bpack_elems * 2);
        unsigned int* ctr = (unsigned int*)((char*)d_ws + ctr_off);
        pack_weights<<<G3, H_DIM, 0, stream>>>(W_hh, W_out, Bh, Bl, WoT, ctr);
        gru_mfma<<<B_ROWS / TB, 512, 0, stream>>>(x, W_ih, b_ih, b_hh,
                                                  Bh, Bl, WoT, b_out, out, ctr);
    } else {
        gru_fallback<<<B_ROWS / TB, 256, 0, stream>>>(x, W_ih, W_hh, b_ih, b_hh,
                                                      W_out, b_out, out);
    }
}